// Round 6
// baseline (200.333 us; speedup 1.0000x reference)
//
#include <hip/hip_runtime.h>
#include <hip/hip_bf16.h>

// Problem constants: B=128 targets, N=50000 data, D=384, DO=2048, K=10.
#define DIM   384
#define DIMO  2048
#define KNN   10
#define KSEL  16
#define FINF  3.0e38f
#define BK    64
#define PITCH 72   // bf16 elems per LDS row: 64 data + 8 pad

typedef __attribute__((ext_vector_type(8))) short short8v;
typedef __attribute__((ext_vector_type(4))) float float4v;

__device__ __forceinline__ unsigned short f2bf(float x) {
    union { float f; unsigned u; } c; c.f = x;
    unsigned lsb = (c.u >> 16) & 1u;                 // round-to-nearest-even
    return (unsigned short)((c.u + 0x7FFFu + lsb) >> 16);
}

// -------------------------------------------------------------------------
// Kernel 1: bf16-MFMA approx score + per-block per-row top-10 candidates.
// approx_score[m][n] = ||d_n||^2 (exact f32) - 2 * bf16dot(t_m, d_n).
// GEMM identical to R3 (passed, absmax 0). Epilogue: parallel parity scan
// (2 threads/row, 64 cols each, strict < keeps lowest idx) + lex (s,idx)
// 2-pointer merge — output order identical to R3's serial scan.
// -------------------------------------------------------------------------
__global__ __launch_bounds__(256) void score_topk_kernel(
    const float* __restrict__ tgt,     // [128][384]
    const float* __restrict__ dat,     // [N][384]
    float* __restrict__ cand_s,        // [128][nblk*10]
    int*   __restrict__ cand_i,        // [128][nblk*10]
    int N, int nblk)
{
    __shared__ unsigned short tAB[2 * 128 * PITCH];           // 36 KB
    unsigned short* tA = tAB;
    unsigned short* tB = tAB + 128 * PITCH;
    float (*sc)[129] = reinterpret_cast<float(*)[129]>(tAB);  // 33 KB overlay
    __shared__ float d2p[128][8];
    __shared__ float d2s[128];
    __shared__ float mgs[64][2][KNN];
    __shared__ int   mgi[64][2][KNN];

    const int tid   = threadIdx.x;
    const int nbase = blockIdx.x * 128;
    const int lane  = tid & 63;
    const int wv    = tid >> 6;
    const int wr    = wv >> 1;
    const int wc    = wv & 1;
    const int r0    = tid >> 3;
    const int c8    = tid & 7;
    const int frow  = lane & 15;
    const int kg    = lane >> 4;

    float4v acc[4][4];
#pragma unroll
    for (int i = 0; i < 4; ++i)
#pragma unroll
        for (int j = 0; j < 4; ++j) acc[i][j] = (float4v){0.f, 0.f, 0.f, 0.f};

    float d2acc[4] = {0.f, 0.f, 0.f, 0.f};

    for (int k0 = 0; k0 < DIM; k0 += BK) {
        __syncthreads();
#pragma unroll
        for (int it = 0; it < 4; ++it) {
            int row = it * 32 + r0;
            const float* s = &tgt[row * DIM + k0 + c8 * 8];
            float4 u0 = *reinterpret_cast<const float4*>(s);
            float4 u1 = *reinterpret_cast<const float4*>(s + 4);
            short8v hh;
            hh[0] = (short)f2bf(u0.x); hh[1] = (short)f2bf(u0.y);
            hh[2] = (short)f2bf(u0.z); hh[3] = (short)f2bf(u0.w);
            hh[4] = (short)f2bf(u1.x); hh[5] = (short)f2bf(u1.y);
            hh[6] = (short)f2bf(u1.z); hh[7] = (short)f2bf(u1.w);
            *reinterpret_cast<short8v*>(&tA[row * PITCH + c8 * 8]) = hh;
        }
#pragma unroll
        for (int it = 0; it < 4; ++it) {
            int row = it * 32 + r0;
            int g   = nbase + row;
            float4 u0 = make_float4(0.f, 0.f, 0.f, 0.f);
            float4 u1 = make_float4(0.f, 0.f, 0.f, 0.f);
            if (g < N) {
                const float* s = &dat[(size_t)g * DIM + k0 + c8 * 8];
                u0 = *reinterpret_cast<const float4*>(s);
                u1 = *reinterpret_cast<const float4*>(s + 4);
            }
            d2acc[it] += u0.x * u0.x + u0.y * u0.y + u0.z * u0.z + u0.w * u0.w
                       + u1.x * u1.x + u1.y * u1.y + u1.z * u1.z + u1.w * u1.w;
            short8v hh;
            hh[0] = (short)f2bf(u0.x); hh[1] = (short)f2bf(u0.y);
            hh[2] = (short)f2bf(u0.z); hh[3] = (short)f2bf(u0.w);
            hh[4] = (short)f2bf(u1.x); hh[5] = (short)f2bf(u1.y);
            hh[6] = (short)f2bf(u1.z); hh[7] = (short)f2bf(u1.w);
            *reinterpret_cast<short8v*>(&tB[row * PITCH + c8 * 8]) = hh;
        }
        __syncthreads();
#pragma unroll
        for (int ks = 0; ks < 2; ++ks) {
            short8v a[4], b[4];
            const int koff = ks * 32 + kg * 8;
#pragma unroll
            for (int f = 0; f < 4; ++f) {
                a[f] = *reinterpret_cast<const short8v*>(
                    &tA[(wr * 64 + f * 16 + frow) * PITCH + koff]);
                b[f] = *reinterpret_cast<const short8v*>(
                    &tB[(wc * 64 + f * 16 + frow) * PITCH + koff]);
            }
#pragma unroll
            for (int fr = 0; fr < 4; ++fr)
#pragma unroll
                for (int fc = 0; fc < 4; ++fc)
                    acc[fr][fc] = __builtin_amdgcn_mfma_f32_16x16x32_bf16(
                        a[fr], b[fc], acc[fr][fc], 0, 0, 0);
        }
    }

    __syncthreads();
#pragma unroll
    for (int it = 0; it < 4; ++it) d2p[it * 32 + r0][c8] = d2acc[it];
    __syncthreads();
    if (tid < 128) {
        float s = 0.f;
#pragma unroll
        for (int j = 0; j < 8; ++j) s += d2p[tid][j];
        d2s[tid] = s;
    }

    const int M = nblk * KNN;
    for (int h = 0; h < 2; ++h) {
        __syncthreads();
        if (wr == h) {
#pragma unroll
            for (int fr = 0; fr < 4; ++fr)
#pragma unroll
                for (int fc = 0; fc < 4; ++fc)
#pragma unroll
                    for (int e = 0; e < 4; ++e) {
                        int lr = fr * 16 + kg * 4 + e;
                        int lc = wc * 64 + fc * 16 + frow;
                        int n  = nbase + lc;
                        sc[lr][lc] = (n < N) ? d2s[lc] - 2.f * acc[fr][fc][e]
                                             : FINF;
                    }
        }
        __syncthreads();
        if (tid < 128) {                 // 2 threads per row, parity-split cols
            int r = tid >> 1, p = tid & 1;
            float ts[KNN];
            int   ti[KNN];
#pragma unroll
            for (int k = 0; k < KNN; ++k) { ts[k] = FINF; ti[k] = 0x7fffffff; }
            for (int c = p; c < 128; c += 2) {   // ascending within parity
                float s = sc[r][c];
                if (s < ts[KNN - 1]) {           // strict < keeps lowest idx
                    ts[KNN - 1] = s;
                    ti[KNN - 1] = nbase + c;
#pragma unroll
                    for (int q = KNN - 1; q > 0; --q) {
                        if (ts[q] < ts[q - 1]) {
                            float fs = ts[q]; ts[q] = ts[q - 1]; ts[q - 1] = fs;
                            int   fi = ti[q]; ti[q] = ti[q - 1]; ti[q - 1] = fi;
                        }
                    }
                }
            }
#pragma unroll
            for (int k = 0; k < KNN; ++k) {
                mgs[r][p][k] = ts[k];
                mgi[r][p][k] = ti[k];
            }
        }
        __syncthreads();
        if (tid < 64) {                  // lex (s,idx) 2-pointer merge -> cand
            int r = tid;
            int i0 = 0, i1 = 0;
            size_t base = (size_t)(h * 64 + r) * M + (size_t)blockIdx.x * KNN;
#pragma unroll
            for (int k = 0; k < KNN; ++k) {
                float s0 = mgs[r][0][i0], s1 = mgs[r][1][i1];
                int   a0 = mgi[r][0][i0], a1 = mgi[r][1][i1];
                bool take0 = (s0 < s1) || (s0 == s1 && a0 < a1);
                if (take0) { cand_s[base + k] = s0; cand_i[base + k] = a0; ++i0; }
                else       { cand_s[base + k] = s1; cand_i[base + k] = a1; ++i1; }
            }
        }
    }
}

// -------------------------------------------------------------------------
// Kernel 2: one block per OUTPUT ROW (b,k), 1280 blocks. Each block
// redundantly selects b's approx top-16 (R4's HW-validated barrier-free
// shuffle tournament), exact-f32 rescores (bit-identical R1 chain), takes
// the final lex top-10, then gathers only row k. Redundant select is L2-hot
// and cheap; buys full-device gather occupancy in a single kernel.
// -------------------------------------------------------------------------
__global__ __launch_bounds__(256) void select_gather_kernel(
    const float* __restrict__ cand_s,  // [B][M]
    const int*   __restrict__ cand_i,  // [B][M]
    const float* __restrict__ tgt,     // [128][384]
    const float* __restrict__ dat,     // [N][384]
    const float* __restrict__ OTin,    // [N][384]
    const float* __restrict__ OTout,   // [N][2048]
    float* __restrict__ out,           // [B*10*384] ++ [B*10*2048]
    int M, int B)
{
    const int u    = blockIdx.x;       // b*KNN + kk
    const int b    = u / KNN;
    const int kk   = u - b * KNN;
    const int tid  = threadIdx.x;
    const int lane = tid & 63;
    const int wv   = tid >> 6;
    const float* rs_ = cand_s + (size_t)b * M;
    const int*   ri_ = cand_i + (size_t)b * M;

    // ---- per-thread sorted top-16 (lex (score, idx)) — static indexing ----
    float ts[KSEL];
    int   ti[KSEL];
#pragma unroll
    for (int k = 0; k < KSEL; ++k) { ts[k] = FINF; ti[k] = 0x7fffffff; }

    for (int j = tid; j < M; j += 256) {
        float s  = rs_[j];
        int   id = ri_[j];
        if (s < ts[KSEL - 1] || (s == ts[KSEL - 1] && id < ti[KSEL - 1])) {
            ts[KSEL - 1] = s;
            ti[KSEL - 1] = id;
#pragma unroll
            for (int p = KSEL - 1; p > 0; --p) {
                bool sw = (ts[p] < ts[p - 1]) ||
                          (ts[p] == ts[p - 1] && ti[p] < ti[p - 1]);
                if (sw) {
                    float fs = ts[p]; ts[p] = ts[p - 1]; ts[p - 1] = fs;
                    int   fi = ti[p]; ti[p] = ti[p - 1]; ti[p - 1] = fi;
                }
            }
        }
    }

    __shared__ float ls[256 * KSEL];   // 16 KB
    __shared__ int   li[256 * KSEL];   // 16 KB
    __shared__ float wout_s[4 * KSEL];
    __shared__ int   wout_i[4 * KSEL];
    __shared__ int   sel16[KSEL];
    __shared__ float ex_s[KSEL];
    __shared__ int   ex_i[KSEL];
    __shared__ int   selk[KNN];

#pragma unroll
    for (int k = 0; k < KSEL; ++k) {
        ls[tid * KSEL + k] = ts[k];
        li[tid * KSEL + k] = ti[k];
    }
    // (each lane only reads its own list slots — no barrier needed)

    // ---- per-wave 64-list head tournament (no barriers; (s,idx) unique) ----
    {
        int   hp = 0;
        float hs = ts[0];
        int   hi = ti[0];
#pragma unroll
        for (int k = 0; k < KSEL; ++k) {
            float ms = hs; int mi = hi;
#pragma unroll
            for (int m = 32; m > 0; m >>= 1) {
                float s2 = __shfl_xor(ms, m);
                int   i2 = __shfl_xor(mi, m);
                if (s2 < ms || (s2 == ms && i2 < mi)) { ms = s2; mi = i2; }
            }
            if (lane == 0) { wout_s[wv * KSEL + k] = ms; wout_i[wv * KSEL + k] = mi; }
            if (hs == ms && hi == mi) {
                if (hp < KSEL - 1) {
                    ++hp;
                    hs = ls[tid * KSEL + hp];
                    hi = li[tid * KSEL + hp];
                } else { hs = FINF; hi = 0x7fffffff; }
            }
        }
    }
    __syncthreads();

    if (wv == 0) {   // merge 4x16 wave winners
        float s = wout_s[lane];
        int   i = wout_i[lane];
#pragma unroll
        for (int k = 0; k < KSEL; ++k) {
            float ms = s; int mi = i;
#pragma unroll
            for (int m = 32; m > 0; m >>= 1) {
                float s2 = __shfl_xor(ms, m);
                int   i2 = __shfl_xor(mi, m);
                if (s2 < ms || (s2 == ms && i2 < mi)) { ms = s2; mi = i2; }
            }
            if (lane == 0) sel16[k] = mi;
            if (s == ms && i == mi) { s = FINF; i = 0x7fffffff; }
        }
    }
    __syncthreads();

    // ---- exact f32 rescore (bit-identical to R1 arithmetic) ----
    if (tid < KSEL) {
        const int n = sel16[tid];
        float d2p_[8] = {0.f, 0.f, 0.f, 0.f, 0.f, 0.f, 0.f, 0.f};
        float dot = 0.f;
        for (int c = 0; c < DIM / 32; ++c) {
#pragma unroll
            for (int j = 0; j < 8; ++j) {
                const float4 v = *reinterpret_cast<const float4*>(
                    &dat[(size_t)n * DIM + c * 32 + j * 4]);
                const float4 t = *reinterpret_cast<const float4*>(
                    &tgt[(size_t)b * DIM + c * 32 + j * 4]);
                d2p_[j] += v.x * v.x + v.y * v.y + v.z * v.z + v.w * v.w;
                dot = fmaf(t.x, v.x, dot);
                dot = fmaf(t.y, v.y, dot);
                dot = fmaf(t.z, v.z, dot);
                dot = fmaf(t.w, v.w, dot);
            }
        }
        float d2 = 0.f;
#pragma unroll
        for (int j = 0; j < 8; ++j) d2 += d2p_[j];
        ex_s[tid] = d2 - 2.f * dot;
        ex_i[tid] = n;
    }
    __syncthreads();

    // ---- final top-10 by (exact score, idx) ----
    if (tid == 0) {
        float fs[KNN]; int fi[KNN];
#pragma unroll
        for (int k = 0; k < KNN; ++k) { fs[k] = FINF; fi[k] = 0x7fffffff; }
        for (int q = 0; q < KSEL; ++q) {
            float s  = ex_s[q];
            int   id = ex_i[q];
            if (s < fs[KNN - 1] || (s == fs[KNN - 1] && id < fi[KNN - 1])) {
                fs[KNN - 1] = s;
                fi[KNN - 1] = id;
#pragma unroll
                for (int p = KNN - 1; p > 0; --p) {
                    bool sw = (fs[p] < fs[p - 1]) ||
                              (fs[p] == fs[p - 1] && fi[p] < fi[p - 1]);
                    if (sw) {
                        float a = fs[p]; fs[p] = fs[p - 1]; fs[p - 1] = a;
                        int   i2 = fi[p]; fi[p] = fi[p - 1]; fi[p - 1] = i2;
                    }
                }
            }
        }
#pragma unroll
        for (int k = 0; k < KNN; ++k) selk[k] = fi[k];
    }
    __syncthreads();

    // ---- gather: only this block's row (b, kk), float4 coalesced ----
    const int idx = selk[kk];
    const size_t o1 = (size_t)B * KNN * DIM;
    const float4* in4  = reinterpret_cast<const float4*>(&OTin[(size_t)idx * DIM]);
    float4*       out4 = reinterpret_cast<float4*>(&out[(size_t)u * DIM]);
    for (int q = tid; q < DIM / 4; q += 256) out4[q] = in4[q];

    const float4* ino4  = reinterpret_cast<const float4*>(&OTout[(size_t)idx * DIMO]);
    float4*       outo4 = reinterpret_cast<float4*>(&out[o1 + (size_t)u * DIMO]);
    for (int q = tid; q < DIMO / 4; q += 256) outo4[q] = ino4[q];
}

extern "C" void kernel_launch(void* const* d_in, const int* in_sizes, int n_in,
                              void* d_out, int out_size, void* d_ws, size_t ws_size,
                              hipStream_t stream) {
    const float* targets = (const float*)d_in[0];
    const float* data    = (const float*)d_in[1];
    const float* OTin    = (const float*)d_in[2];
    const float* OTout   = (const float*)d_in[3];
    float* out = (float*)d_out;

    const int B = in_sizes[0] / DIM;   // 128
    const int N = in_sizes[1] / DIM;   // 50000

    const int nblk = (N + 127) / 128;  // 391
    const int M    = nblk * KNN;       // 3910

    float* cand_s = (float*)d_ws;                       // B*M floats
    int*   cand_i = (int*)(cand_s + (size_t)B * M);     // B*M ints

    score_topk_kernel<<<nblk, 256, 0, stream>>>(targets, data, cand_s, cand_i, N, nblk);
    select_gather_kernel<<<B * KNN, 256, 0, stream>>>(
        cand_s, cand_i, targets, data, OTin, OTout, out, M, B);
}

// Round 7
// 146.302 us; speedup vs baseline: 1.3693x; 1.3693x over previous
//
#include <hip/hip_runtime.h>
#include <hip/hip_bf16.h>

// Problem constants: B=128 targets, N=50000 data, D=384, DO=2048, K=10.
#define DIM   384
#define DIMO  2048
#define KNN   10
#define KSEL  16
#define FINF  3.0e38f
#define BK    64
#define PITCH 72   // bf16 elems per LDS row: 64 data + 8 pad

typedef __attribute__((ext_vector_type(8))) short short8v;
typedef __attribute__((ext_vector_type(4))) float float4v;

__device__ __forceinline__ unsigned short f2bf(float x) {
    union { float f; unsigned u; } c; c.f = x;
    unsigned lsb = (c.u >> 16) & 1u;                 // round-to-nearest-even
    return (unsigned short)((c.u + 0x7FFFu + lsb) >> 16);
}

// -------------------------------------------------------------------------
// Kernel 1: bf16-MFMA approx score + per-block per-row top-10 candidates.
// (identical to R6's K1, which passed with absmax 0)
// -------------------------------------------------------------------------
__global__ __launch_bounds__(256) void score_topk_kernel(
    const float* __restrict__ tgt,     // [128][384]
    const float* __restrict__ dat,     // [N][384]
    float* __restrict__ cand_s,        // [128][nblk*10]
    int*   __restrict__ cand_i,        // [128][nblk*10]
    int N, int nblk)
{
    __shared__ unsigned short tAB[2 * 128 * PITCH];           // 36 KB
    unsigned short* tA = tAB;
    unsigned short* tB = tAB + 128 * PITCH;
    float (*sc)[129] = reinterpret_cast<float(*)[129]>(tAB);  // 33 KB overlay
    __shared__ float d2p[128][8];
    __shared__ float d2s[128];
    __shared__ float mgs[64][2][KNN];
    __shared__ int   mgi[64][2][KNN];

    const int tid   = threadIdx.x;
    const int nbase = blockIdx.x * 128;
    const int lane  = tid & 63;
    const int wv    = tid >> 6;
    const int wr    = wv >> 1;
    const int wc    = wv & 1;
    const int r0    = tid >> 3;
    const int c8    = tid & 7;
    const int frow  = lane & 15;
    const int kg    = lane >> 4;

    float4v acc[4][4];
#pragma unroll
    for (int i = 0; i < 4; ++i)
#pragma unroll
        for (int j = 0; j < 4; ++j) acc[i][j] = (float4v){0.f, 0.f, 0.f, 0.f};

    float d2acc[4] = {0.f, 0.f, 0.f, 0.f};

    for (int k0 = 0; k0 < DIM; k0 += BK) {
        __syncthreads();
#pragma unroll
        for (int it = 0; it < 4; ++it) {
            int row = it * 32 + r0;
            const float* s = &tgt[row * DIM + k0 + c8 * 8];
            float4 u0 = *reinterpret_cast<const float4*>(s);
            float4 u1 = *reinterpret_cast<const float4*>(s + 4);
            short8v hh;
            hh[0] = (short)f2bf(u0.x); hh[1] = (short)f2bf(u0.y);
            hh[2] = (short)f2bf(u0.z); hh[3] = (short)f2bf(u0.w);
            hh[4] = (short)f2bf(u1.x); hh[5] = (short)f2bf(u1.y);
            hh[6] = (short)f2bf(u1.z); hh[7] = (short)f2bf(u1.w);
            *reinterpret_cast<short8v*>(&tA[row * PITCH + c8 * 8]) = hh;
        }
#pragma unroll
        for (int it = 0; it < 4; ++it) {
            int row = it * 32 + r0;
            int g   = nbase + row;
            float4 u0 = make_float4(0.f, 0.f, 0.f, 0.f);
            float4 u1 = make_float4(0.f, 0.f, 0.f, 0.f);
            if (g < N) {
                const float* s = &dat[(size_t)g * DIM + k0 + c8 * 8];
                u0 = *reinterpret_cast<const float4*>(s);
                u1 = *reinterpret_cast<const float4*>(s + 4);
            }
            d2acc[it] += u0.x * u0.x + u0.y * u0.y + u0.z * u0.z + u0.w * u0.w
                       + u1.x * u1.x + u1.y * u1.y + u1.z * u1.z + u1.w * u1.w;
            short8v hh;
            hh[0] = (short)f2bf(u0.x); hh[1] = (short)f2bf(u0.y);
            hh[2] = (short)f2bf(u0.z); hh[3] = (short)f2bf(u0.w);
            hh[4] = (short)f2bf(u1.x); hh[5] = (short)f2bf(u1.y);
            hh[6] = (short)f2bf(u1.z); hh[7] = (short)f2bf(u1.w);
            *reinterpret_cast<short8v*>(&tB[row * PITCH + c8 * 8]) = hh;
        }
        __syncthreads();
#pragma unroll
        for (int ks = 0; ks < 2; ++ks) {
            short8v a[4], b[4];
            const int koff = ks * 32 + kg * 8;
#pragma unroll
            for (int f = 0; f < 4; ++f) {
                a[f] = *reinterpret_cast<const short8v*>(
                    &tA[(wr * 64 + f * 16 + frow) * PITCH + koff]);
                b[f] = *reinterpret_cast<const short8v*>(
                    &tB[(wc * 64 + f * 16 + frow) * PITCH + koff]);
            }
#pragma unroll
            for (int fr = 0; fr < 4; ++fr)
#pragma unroll
                for (int fc = 0; fc < 4; ++fc)
                    acc[fr][fc] = __builtin_amdgcn_mfma_f32_16x16x32_bf16(
                        a[fr], b[fc], acc[fr][fc], 0, 0, 0);
        }
    }

    __syncthreads();
#pragma unroll
    for (int it = 0; it < 4; ++it) d2p[it * 32 + r0][c8] = d2acc[it];
    __syncthreads();
    if (tid < 128) {
        float s = 0.f;
#pragma unroll
        for (int j = 0; j < 8; ++j) s += d2p[tid][j];
        d2s[tid] = s;
    }

    const int M = nblk * KNN;
    for (int h = 0; h < 2; ++h) {
        __syncthreads();
        if (wr == h) {
#pragma unroll
            for (int fr = 0; fr < 4; ++fr)
#pragma unroll
                for (int fc = 0; fc < 4; ++fc)
#pragma unroll
                    for (int e = 0; e < 4; ++e) {
                        int lr = fr * 16 + kg * 4 + e;
                        int lc = wc * 64 + fc * 16 + frow;
                        int n  = nbase + lc;
                        sc[lr][lc] = (n < N) ? d2s[lc] - 2.f * acc[fr][fc][e]
                                             : FINF;
                    }
        }
        __syncthreads();
        if (tid < 128) {                 // 2 threads per row, parity-split cols
            int r = tid >> 1, p = tid & 1;
            float ts[KNN];
            int   ti[KNN];
#pragma unroll
            for (int k = 0; k < KNN; ++k) { ts[k] = FINF; ti[k] = 0x7fffffff; }
            for (int c = p; c < 128; c += 2) {   // ascending within parity
                float s = sc[r][c];
                if (s < ts[KNN - 1]) {           // strict < keeps lowest idx
                    ts[KNN - 1] = s;
                    ti[KNN - 1] = nbase + c;
#pragma unroll
                    for (int q = KNN - 1; q > 0; --q) {
                        if (ts[q] < ts[q - 1]) {
                            float fs = ts[q]; ts[q] = ts[q - 1]; ts[q - 1] = fs;
                            int   fi = ti[q]; ti[q] = ti[q - 1]; ti[q - 1] = fi;
                        }
                    }
                }
            }
#pragma unroll
            for (int k = 0; k < KNN; ++k) {
                mgs[r][p][k] = ts[k];
                mgi[r][p][k] = ti[k];
            }
        }
        __syncthreads();
        if (tid < 64) {                  // lex (s,idx) 2-pointer merge -> cand
            int r = tid;
            int i0 = 0, i1 = 0;
            size_t base = (size_t)(h * 64 + r) * M + (size_t)blockIdx.x * KNN;
#pragma unroll
            for (int k = 0; k < KNN; ++k) {
                float s0 = mgs[r][0][i0], s1 = mgs[r][1][i1];
                int   a0 = mgi[r][0][i0], a1 = mgi[r][1][i1];
                bool take0 = (s0 < s1) || (s0 == s1 && a0 < a1);
                if (take0) { cand_s[base + k] = s0; cand_i[base + k] = a0; ++i0; }
                else       { cand_s[base + k] = s1; cand_i[base + k] = a1; ++i1; }
            }
        }
    }
}

// -------------------------------------------------------------------------
// Kernel 2: merge candidates -> approx top-16 (barrier-free shuffle
// tournament), exact-f32 rescore (bit-identical R1 chain), top-10 -> seldev.
// (identical to R3's proven select path)
// -------------------------------------------------------------------------
__global__ __launch_bounds__(256) void select_rescore_kernel(
    const float* __restrict__ cand_s,  // [B][M]
    const int*   __restrict__ cand_i,  // [B][M]
    const float* __restrict__ tgt,     // [128][384]
    const float* __restrict__ dat,     // [N][384]
    int* __restrict__ seldev,          // [B][10]
    int M)
{
    const int b    = blockIdx.x;
    const int tid  = threadIdx.x;
    const int lane = tid & 63;
    const int wv   = tid >> 6;
    const float* rs_ = cand_s + (size_t)b * M;
    const int*   ri_ = cand_i + (size_t)b * M;

    float ts[KSEL];
    int   ti[KSEL];
#pragma unroll
    for (int k = 0; k < KSEL; ++k) { ts[k] = FINF; ti[k] = 0x7fffffff; }

    for (int j = tid; j < M; j += 256) {
        float s  = rs_[j];
        int   id = ri_[j];
        if (s < ts[KSEL - 1] || (s == ts[KSEL - 1] && id < ti[KSEL - 1])) {
            ts[KSEL - 1] = s;
            ti[KSEL - 1] = id;
#pragma unroll
            for (int p = KSEL - 1; p > 0; --p) {
                bool sw = (ts[p] < ts[p - 1]) ||
                          (ts[p] == ts[p - 1] && ti[p] < ti[p - 1]);
                if (sw) {
                    float fs = ts[p]; ts[p] = ts[p - 1]; ts[p - 1] = fs;
                    int   fi = ti[p]; ti[p] = ti[p - 1]; ti[p - 1] = fi;
                }
            }
        }
    }

    __shared__ float ls[256 * KSEL];   // 16 KB
    __shared__ int   li[256 * KSEL];   // 16 KB
    __shared__ float wout_s[4 * KSEL];
    __shared__ int   wout_i[4 * KSEL];
    __shared__ int   sel16[KSEL];
    __shared__ float ex_s[KSEL];
    __shared__ int   ex_i[KSEL];

#pragma unroll
    for (int k = 0; k < KSEL; ++k) {
        ls[tid * KSEL + k] = ts[k];
        li[tid * KSEL + k] = ti[k];
    }

    {
        int   hp = 0;
        float hs = ts[0];
        int   hi = ti[0];
#pragma unroll
        for (int k = 0; k < KSEL; ++k) {
            float ms = hs; int mi = hi;
#pragma unroll
            for (int m = 32; m > 0; m >>= 1) {
                float s2 = __shfl_xor(ms, m);
                int   i2 = __shfl_xor(mi, m);
                if (s2 < ms || (s2 == ms && i2 < mi)) { ms = s2; mi = i2; }
            }
            if (lane == 0) { wout_s[wv * KSEL + k] = ms; wout_i[wv * KSEL + k] = mi; }
            if (hs == ms && hi == mi) {
                if (hp < KSEL - 1) {
                    ++hp;
                    hs = ls[tid * KSEL + hp];
                    hi = li[tid * KSEL + hp];
                } else { hs = FINF; hi = 0x7fffffff; }
            }
        }
    }
    __syncthreads();

    if (wv == 0) {
        float s = wout_s[lane];
        int   i = wout_i[lane];
#pragma unroll
        for (int k = 0; k < KSEL; ++k) {
            float ms = s; int mi = i;
#pragma unroll
            for (int m = 32; m > 0; m >>= 1) {
                float s2 = __shfl_xor(ms, m);
                int   i2 = __shfl_xor(mi, m);
                if (s2 < ms || (s2 == ms && i2 < mi)) { ms = s2; mi = i2; }
            }
            if (lane == 0) sel16[k] = mi;
            if (s == ms && i == mi) { s = FINF; i = 0x7fffffff; }
        }
    }
    __syncthreads();

    if (tid < KSEL) {
        const int n = sel16[tid];
        float d2p_[8] = {0.f, 0.f, 0.f, 0.f, 0.f, 0.f, 0.f, 0.f};
        float dot = 0.f;
        for (int c = 0; c < DIM / 32; ++c) {
#pragma unroll
            for (int j = 0; j < 8; ++j) {
                const float4 v = *reinterpret_cast<const float4*>(
                    &dat[(size_t)n * DIM + c * 32 + j * 4]);
                const float4 t = *reinterpret_cast<const float4*>(
                    &tgt[(size_t)b * DIM + c * 32 + j * 4]);
                d2p_[j] += v.x * v.x + v.y * v.y + v.z * v.z + v.w * v.w;
                dot = fmaf(t.x, v.x, dot);
                dot = fmaf(t.y, v.y, dot);
                dot = fmaf(t.z, v.z, dot);
                dot = fmaf(t.w, v.w, dot);
            }
        }
        float d2 = 0.f;
#pragma unroll
        for (int j = 0; j < 8; ++j) d2 += d2p_[j];
        ex_s[tid] = d2 - 2.f * dot;
        ex_i[tid] = n;
    }
    __syncthreads();

    if (tid == 0) {
        float fs[KNN]; int fi[KNN];
#pragma unroll
        for (int k = 0; k < KNN; ++k) { fs[k] = FINF; fi[k] = 0x7fffffff; }
        for (int q = 0; q < KSEL; ++q) {
            float s  = ex_s[q];
            int   id = ex_i[q];
            if (s < fs[KNN - 1] || (s == fs[KNN - 1] && id < fi[KNN - 1])) {
                fs[KNN - 1] = s;
                fi[KNN - 1] = id;
#pragma unroll
                for (int p = KNN - 1; p > 0; --p) {
                    bool sw = (fs[p] < fs[p - 1]) ||
                              (fs[p] == fs[p - 1] && fi[p] < fi[p - 1]);
                    if (sw) {
                        float a = fs[p]; fs[p] = fs[p - 1]; fs[p - 1] = a;
                        int   i2 = fi[p]; fi[p] = fi[p - 1]; fi[p - 1] = i2;
                    }
                }
            }
        }
#pragma unroll
        for (int k = 0; k < KNN; ++k) seldev[b * KNN + k] = fi[k];
    }
}

// -------------------------------------------------------------------------
// Kernel 3: gather into DEVICE staging buffer (ws), not d_out.
// One block per (target, k) pair, 1280 blocks.
// -------------------------------------------------------------------------
__global__ __launch_bounds__(256) void gather_kernel(
    const int* __restrict__ seldev,    // [B*10]
    const float* __restrict__ OTin,    // [N][384]
    const float* __restrict__ OTout,   // [N][2048]
    float* __restrict__ outstg,        // staging: [B*10*384] ++ [B*10*2048]
    int B)
{
    const int bid = blockIdx.x;
    const int tid = threadIdx.x;
    const int idx = seldev[bid];
    const size_t o1 = (size_t)B * KNN * DIM;

    const float4* in4  = reinterpret_cast<const float4*>(&OTin[(size_t)idx * DIM]);
    float4*       out4 = reinterpret_cast<float4*>(&outstg[(size_t)bid * DIM]);
    for (int q = tid; q < DIM / 4; q += 256) out4[q] = in4[q];

    const float4* ino4  = reinterpret_cast<const float4*>(&OTout[(size_t)idx * DIMO]);
    float4*       outo4 = reinterpret_cast<float4*>(&outstg[o1 + (size_t)bid * DIMO]);
    for (int q = tid; q < DIMO / 4; q += 256) outo4[q] = ino4[q];
}

extern "C" void kernel_launch(void* const* d_in, const int* in_sizes, int n_in,
                              void* d_out, int out_size, void* d_ws, size_t ws_size,
                              hipStream_t stream) {
    const float* targets = (const float*)d_in[0];
    const float* data    = (const float*)d_in[1];
    const float* OTin    = (const float*)d_in[2];
    const float* OTout   = (const float*)d_in[3];

    const int B = in_sizes[0] / DIM;   // 128
    const int N = in_sizes[1] / DIM;   // 50000

    const int nblk = (N + 127) / 128;  // 391
    const int M    = nblk * KNN;       // 3910

    float* cand_s = (float*)d_ws;                       // B*M floats
    int*   cand_i = (int*)(cand_s + (size_t)B * M);     // B*M ints
    int*   seldev = (int*)(cand_i + (size_t)B * M);     // B*KNN ints
    float* outstg = (float*)(seldev + (size_t)B * KNN); // out_size floats (16B-aligned)

    score_topk_kernel<<<nblk, 256, 0, stream>>>(targets, data, cand_s, cand_i, N, nblk);
    select_rescore_kernel<<<B, 256, 0, stream>>>(cand_s, cand_i, targets, data, seldev, M);
    gather_kernel<<<B * KNN, 256, 0, stream>>>(seldev, OTin, OTout, outstg, B);
    hipMemcpyAsync(d_out, outstg, (size_t)out_size * sizeof(float),
                   hipMemcpyDeviceToDevice, stream);
}